// Round 1
// baseline (12884.097 us; speedup 1.0000x reference)
//
#include <hip/hip_runtime.h>
#include <hip/hip_bf16.h>
#include <stdint.h>

typedef unsigned short u16;
typedef short bf16x8 __attribute__((ext_vector_type(8)));
typedef float f32x4 __attribute__((ext_vector_type(4)));

#define T_STEPS 512
#define BATCH   128
#define EDIM    256
#define HDIM    512
#define NGROUPS 4
#define MROWS   32            // batch rows per group
#define KS_H    16            // K-slices of 32 covering Wh (512)
#define KS_TOT  24            // + Wx (256) -> K = 768
#define POST_TARGET 64u       // waves per group

// ---- workspace layout (bytes) ----
#define FLAGS_OFF   0                          // 4*(513)*4 = 8208 -> pad to 16384
#define HBUF_OFF    16384                      // 2*4*32*512*2  = 262144
#define BIAS_OFF    (16384 + 262144)           // 2048*4 = 8192
#define WFRAG_OFF   (BIAS_OFF + 8192)          // 768*2048*2 = 3145728
#define XBF_OFF     (WFRAG_OFF + 3145728)      // 512*128*256*2 = 33554432
// total ~35.3 MB

__device__ __forceinline__ u16 f2bf(float f) {
  union { float f; uint32_t u; } v; v.f = f;
  return (u16)((v.u + 0x7fffu + ((v.u >> 16) & 1u)) >> 16);   // RNE
}

__device__ __forceinline__ float sigmoidf_fast(float x) {
  return __builtin_amdgcn_rcpf(1.0f + __builtin_amdgcn_exp2f(-1.442695041f * x));
}
__device__ __forceinline__ float tanhf_fast(float x) {
  return 1.0f - 2.0f * __builtin_amdgcn_rcpf(1.0f + __builtin_amdgcn_exp2f(2.885390082f * x));
}

// inputs fp32 -> bf16, same [T*B, E] row-major layout. 4 elems/thread, exact grid.
__global__ void __launch_bounds__(256) k_prep_x(const float* __restrict__ in,
                                                u16* __restrict__ out) {
  int i = blockIdx.x * 256 + threadIdx.x;     // 4,194,304 threads
  float4 v = reinterpret_cast<const float4*>(in)[i];
  ushort4 o; o.x = f2bf(v.x); o.y = f2bf(v.y); o.z = f2bf(v.z); o.w = f2bf(v.w);
  reinterpret_cast<ushort4*>(out)[i] = o;
}

// Pack [Wh;Wx] into per-wave MFMA B-fragment layout (bf16), gate-interleaved
// col(w,u,g) = 32w + 8g + u, unit = 8w + u.
// element index: ((w*2+nt)*24+ks)*512 + lane*8 + e  == t*8 + e
__global__ void __launch_bounds__(256) k_prep_w(
    const float* __restrict__ whi, const float* __restrict__ whf,
    const float* __restrict__ who, const float* __restrict__ whc,
    const float* __restrict__ wxi, const float* __restrict__ wxf,
    const float* __restrict__ wxo, const float* __restrict__ wxc,
    u16* __restrict__ wfrag) {
  int t = blockIdx.x * 256 + threadIdx.x;     // 196,608 threads
  int lane = t & 63;
  int rest = t >> 6;                          // = (w*2+nt)*24 + ks
  int ks = rest % 24;
  int nt = (rest / 24) & 1;
  int w  = rest / 48;
  int cl = nt * 16 + (lane & 15);             // 0..31 within wave's col group
  int u  = cl & 7;
  int gi = cl >> 3;                           // 0=i 1=f 2=o 3=c
  int col = w * 8 + u;                        // hidden unit
  const float* wh = (gi == 0) ? whi : (gi == 1) ? whf : (gi == 2) ? who : whc;
  const float* wx = (gi == 0) ? wxi : (gi == 1) ? wxf : (gi == 2) ? wxo : wxc;
  int kbase = ks * 32 + ((lane >> 4) & 3) * 8;
  u16 vals[8];
#pragma unroll
  for (int e = 0; e < 8; ++e) {
    int k = kbase + e;
    float s = (k < HDIM) ? wh[(size_t)k * HDIM + col]
                         : wx[(size_t)(k - HDIM) * HDIM + col];
    vals[e] = f2bf(s);
  }
  ushort4* d4 = reinterpret_cast<ushort4*>(wfrag + (size_t)t * 8);
  ushort4 a; a.x = vals[0]; a.y = vals[1]; a.z = vals[2]; a.w = vals[3];
  ushort4 b; b.x = vals[4]; b.y = vals[5]; b.z = vals[6]; b.w = vals[7];
  d4[0] = a; d4[1] = b;
}

// bias packed to interleaved col order: bpk[32w + 8g + u] = b_g[8w+u]
__global__ void __launch_bounds__(256) k_prep_b(
    const float* __restrict__ bi, const float* __restrict__ bf_,
    const float* __restrict__ bo, const float* __restrict__ bc,
    float* __restrict__ bpk) {
  int t = blockIdx.x * 256 + threadIdx.x;     // 2048
  int cl = t & 31, w = t >> 5;
  int u = cl & 7, gi = cl >> 3;
  const float* b = (gi == 0) ? bi : (gi == 1) ? bf_ : (gi == 2) ? bo : bc;
  bpk[t] = b[w * 8 + u];
}

// Persistent fused LSTM: 64 blocks x 4 waves; wave (g = wave-in-block, w = blockIdx)
// owns [32 rows, 32 preact cols] for every timestep. No __syncthreads in the loop.
__global__ void __launch_bounds__(256) k_lstm(
    const u16* __restrict__ xbf, const u16* __restrict__ wfrag,
    const float* __restrict__ bpk, u16* hbuf,
    uint32_t* flags, float* __restrict__ out) {
  const int lane = threadIdx.x & 63;
  const int g    = threadIdx.x >> 6;          // group 0..3
  const int w    = blockIdx.x;                // unit-slice 0..63
  const int l15  = lane & 15;
  const int l4   = (lane >> 4) & 3;
  const int gh   = (lane >> 3) & 1;
  const int u    = lane & 7;

  // persistent B fragments: [768 K, 32 cols] = 48 x bf16x8 = 192 VGPR
  bf16x8 Bf[2][KS_TOT];
  {
    const bf16x8* wfb = reinterpret_cast<const bf16x8*>(wfrag);
#pragma unroll
    for (int nt = 0; nt < 2; ++nt)
#pragma unroll
      for (int ks = 0; ks < KS_TOT; ++ks)
        Bf[nt][ks] = wfb[((size_t)(w * 2 + nt) * KS_TOT + ks) * 64 + lane];
  }
  const float bias0 = bpk[w * 32 + l15];
  const float bias1 = bpk[w * 32 + 16 + l15];

  float Cst[2][4] = {};                       // cell state, unit u, rows (mt,j)
  uint32_t* fl = flags + g * (T_STEPS + 1);

  for (int t = 0; t < T_STEPS; ++t) {
    if (t > 0) {
      int guard = 0;
      while (__hip_atomic_load(&fl[t], __ATOMIC_RELAXED, __HIP_MEMORY_SCOPE_AGENT)
             < POST_TARGET) {
        __builtin_amdgcn_s_sleep(1);
        if (++guard > (1 << 22)) break;       // anti-hang valve
      }
      __threadfence();                        // acquire: see other blocks' H writes
    }

    f32x4 acc[2][2] = {};
    if (t > 0) {                              // H part (H^0 == 0 -> skip)
      const u16* hb = hbuf + ((size_t)((t & 1) * NGROUPS + g)) * MROWS * HDIM;
      const u16* h0 = hb + (size_t)l15 * HDIM + l4 * 8;
#pragma unroll
      for (int ks = 0; ks < KS_H; ++ks) {
        bf16x8 a0 = *reinterpret_cast<const bf16x8*>(h0 + ks * 32);
        bf16x8 a1 = *reinterpret_cast<const bf16x8*>(h0 + (size_t)16 * HDIM + ks * 32);
        acc[0][0] = __builtin_amdgcn_mfma_f32_16x16x32_bf16(a0, Bf[0][ks], acc[0][0], 0, 0, 0);
        acc[0][1] = __builtin_amdgcn_mfma_f32_16x16x32_bf16(a0, Bf[1][ks], acc[0][1], 0, 0, 0);
        acc[1][0] = __builtin_amdgcn_mfma_f32_16x16x32_bf16(a1, Bf[0][ks], acc[1][0], 0, 0, 0);
        acc[1][1] = __builtin_amdgcn_mfma_f32_16x16x32_bf16(a1, Bf[1][ks], acc[1][1], 0, 0, 0);
      }
    }
    {                                         // x part (K = 256)
      const u16* xr = xbf + ((size_t)(t * BATCH + g * MROWS + l15)) * EDIM + l4 * 8;
#pragma unroll
      for (int ks = 0; ks < 8; ++ks) {
        bf16x8 a0 = *reinterpret_cast<const bf16x8*>(xr + ks * 32);
        bf16x8 a1 = *reinterpret_cast<const bf16x8*>(xr + (size_t)16 * EDIM + ks * 32);
        acc[0][0] = __builtin_amdgcn_mfma_f32_16x16x32_bf16(a0, Bf[0][KS_H + ks], acc[0][0], 0, 0, 0);
        acc[0][1] = __builtin_amdgcn_mfma_f32_16x16x32_bf16(a0, Bf[1][KS_H + ks], acc[0][1], 0, 0, 0);
        acc[1][0] = __builtin_amdgcn_mfma_f32_16x16x32_bf16(a1, Bf[0][KS_H + ks], acc[1][0], 0, 0, 0);
        acc[1][1] = __builtin_amdgcn_mfma_f32_16x16x32_bf16(a1, Bf[1][KS_H + ks], acc[1][1], 0, 0, 0);
      }
    }

    // gating: lane pair (l, l^8) holds the 4 gates of unit u for each row
    u16* hn = hbuf + ((size_t)(((t + 1) & 1) * NGROUPS + g)) * MROWS * HDIM;
#pragma unroll
    for (int mt = 0; mt < 2; ++mt) {
#pragma unroll
      for (int j = 0; j < 4; ++j) {
        float p0 = acc[mt][0][j] + bias0;     // gate (gh)     of unit u
        float p1 = acc[mt][1][j] + bias1;     // gate (2+gh)   of unit u
        float q0 = __shfl_xor(p0, 8);
        float q1 = __shfl_xor(p1, 8);
        float pi = gh ? q0 : p0;
        float pf = gh ? p0 : q0;
        float po = gh ? q1 : p1;
        float pc = gh ? p1 : q1;
        float I = sigmoidf_fast(pi);
        float F = sigmoidf_fast(pf);
        float O = sigmoidf_fast(po);
        float Ct = tanhf_fast(pc);
        float c = F * Cst[mt][j] + I * Ct;
        Cst[mt][j] = c;
        float h = tanhf_fast(c) * O;
        int row = mt * 16 + l4 * 4 + j;
        int brow = g * MROWS + row;
        int hcol = w * 8 + u;
        if (gh == 0) {                        // one writer per (row, unit)
          hn[row * HDIM + hcol] = f2bf(h);
          out[((size_t)t * BATCH + brow) * HDIM + hcol] = h;
          if (t == T_STEPS - 1) {
            size_t base = (size_t)T_STEPS * BATCH * HDIM;
            out[base + (size_t)brow * HDIM + hcol] = h;                       // H final
            out[base + (size_t)BATCH * HDIM + (size_t)brow * HDIM + hcol] = c; // C final
          }
        }
      }
    }

    __threadfence();                          // release H writes
    if (lane == 0)
      __hip_atomic_fetch_add(&fl[t + 1], 1u, __ATOMIC_RELAXED, __HIP_MEMORY_SCOPE_AGENT);
  }
}

extern "C" void kernel_launch(void* const* d_in, const int* in_sizes, int n_in,
                              void* d_out, int out_size, void* d_ws, size_t ws_size,
                              hipStream_t stream) {
  const float* inp = (const float*)d_in[0];
  const float* wxi = (const float*)d_in[1];
  const float* whi = (const float*)d_in[2];
  const float* bi  = (const float*)d_in[3];
  const float* wxf = (const float*)d_in[4];
  const float* whf = (const float*)d_in[5];
  const float* bf_ = (const float*)d_in[6];
  const float* wxo = (const float*)d_in[7];
  const float* who = (const float*)d_in[8];
  const float* bo  = (const float*)d_in[9];
  const float* wxc = (const float*)d_in[10];
  const float* whc = (const float*)d_in[11];
  const float* bc  = (const float*)d_in[12];

  char* ws = (char*)d_ws;
  uint32_t* flags = (uint32_t*)(ws + FLAGS_OFF);
  float*    bpk   = (float*)(ws + BIAS_OFF);
  u16*      hbuf  = (u16*)(ws + HBUF_OFF);
  u16*      wfrag = (u16*)(ws + WFRAG_OFF);
  u16*      xbf   = (u16*)(ws + XBF_OFF);
  float*    out   = (float*)d_out;

  hipMemsetAsync(flags, 0, (size_t)NGROUPS * (T_STEPS + 1) * sizeof(uint32_t), stream);
  k_prep_x<<<16384, 256, 0, stream>>>(inp, xbf);
  k_prep_w<<<768, 256, 0, stream>>>(whi, whf, who, whc, wxi, wxf, wxo, wxc, wfrag);
  k_prep_b<<<8, 256, 0, stream>>>(bi, bf_, bo, bc, bpk);
  k_lstm<<<64, 256, 0, stream>>>(xbf, wfrag, bpk, hbuf, flags, out);
}

// Round 2
// 5460.575 us; speedup vs baseline: 2.3595x; 2.3595x over previous
//
#include <hip/hip_runtime.h>
#include <hip/hip_bf16.h>
#include <stdint.h>

typedef unsigned short u16;
typedef short bf16x8 __attribute__((ext_vector_type(8)));
typedef float f32x4 __attribute__((ext_vector_type(4)));

#define T_STEPS 512
#define BATCH   128
#define EDIM    256
#define HDIM    512
#define NGROUPS 4
#define MROWS   32            // batch rows per group
#define KS_H    16            // K-slices of 32 covering Wh (512)
#define KS_TOT  24            // + Wx (256) -> K = 768

// ---- workspace layout (bytes) ----
#define FLAGS_OFF   0                          // 4*64*4 = 1024 -> pad to 16384
#define HBUF_OFF    16384                      // 2*4*32*512*2  = 262144
#define BIAS_OFF    (16384 + 262144)           // 2048*4 = 8192
#define WFRAG_OFF   (BIAS_OFF + 8192)          // 768*2048*2 = 3145728
#define XBF_OFF     (WFRAG_OFF + 3145728)      // 512*128*256*2 = 33554432
// total ~35.3 MB

__device__ __forceinline__ u16 f2bf(float f) {
  union { float f; uint32_t u; } v; v.f = f;
  return (u16)((v.u + 0x7fffu + ((v.u >> 16) & 1u)) >> 16);   // RNE
}

__device__ __forceinline__ float sigmoidf_fast(float x) {
  return __builtin_amdgcn_rcpf(1.0f + __builtin_amdgcn_exp2f(-1.442695041f * x));
}
__device__ __forceinline__ float tanhf_fast(float x) {
  return 1.0f - 2.0f * __builtin_amdgcn_rcpf(1.0f + __builtin_amdgcn_exp2f(2.885390082f * x));
}

// ---- Infinity-Cache-coherent access (sc0 sc1 = bypass L1+L2, coherent at IF) ----
__device__ __forceinline__ bf16x8 ifc_load_b128(const void* p) {
  bf16x8 r;
  asm volatile("global_load_dwordx4 %0, %1, off sc0 sc1" : "=v"(r) : "v"(p));
  return r;  // caller must s_waitcnt vmcnt before use
}
__device__ __forceinline__ uint32_t ifc_poll_u32(const uint32_t* p) {
  uint32_t r;
  asm volatile("global_load_dword %0, %1, off sc0 sc1\n\ts_waitcnt vmcnt(0)"
               : "=v"(r) : "v"(p) : "memory");
  return r;
}
__device__ __forceinline__ void ifc_store_u32(uint32_t* p, uint32_t v) {
  asm volatile("global_store_dword %0, %1, off sc0 sc1" :: "v"(p), "v"(v) : "memory");
}

// inputs fp32 -> bf16, same [T*B, E] row-major layout. 4 elems/thread, exact grid.
__global__ void __launch_bounds__(256) k_prep_x(const float* __restrict__ in,
                                                u16* __restrict__ out) {
  int i = blockIdx.x * 256 + threadIdx.x;     // 4,194,304 threads
  float4 v = reinterpret_cast<const float4*>(in)[i];
  ushort4 o; o.x = f2bf(v.x); o.y = f2bf(v.y); o.z = f2bf(v.z); o.w = f2bf(v.w);
  reinterpret_cast<ushort4*>(out)[i] = o;
}

// Pack [Wh;Wx] into per-wave MFMA B-fragment layout (bf16), gate-interleaved
// col(w,u,g) = 32w + 8g + u, unit = 8w + u.
__global__ void __launch_bounds__(256) k_prep_w(
    const float* __restrict__ whi, const float* __restrict__ whf,
    const float* __restrict__ who, const float* __restrict__ whc,
    const float* __restrict__ wxi, const float* __restrict__ wxf,
    const float* __restrict__ wxo, const float* __restrict__ wxc,
    u16* __restrict__ wfrag) {
  int t = blockIdx.x * 256 + threadIdx.x;     // 196,608 threads
  int lane = t & 63;
  int rest = t >> 6;                          // = (w*2+nt)*24 + ks
  int ks = rest % 24;
  int nt = (rest / 24) & 1;
  int w  = rest / 48;
  int cl = nt * 16 + (lane & 15);             // 0..31 within wave's col group
  int u  = cl & 7;
  int gi = cl >> 3;                           // 0=i 1=f 2=o 3=c
  int col = w * 8 + u;                        // hidden unit
  const float* wh = (gi == 0) ? whi : (gi == 1) ? whf : (gi == 2) ? who : whc;
  const float* wx = (gi == 0) ? wxi : (gi == 1) ? wxf : (gi == 2) ? wxo : wxc;
  int kbase = ks * 32 + ((lane >> 4) & 3) * 8;
  u16 vals[8];
#pragma unroll
  for (int e = 0; e < 8; ++e) {
    int k = kbase + e;
    float s = (k < HDIM) ? wh[(size_t)k * HDIM + col]
                         : wx[(size_t)(k - HDIM) * HDIM + col];
    vals[e] = f2bf(s);
  }
  ushort4* d4 = reinterpret_cast<ushort4*>(wfrag + (size_t)t * 8);
  ushort4 a; a.x = vals[0]; a.y = vals[1]; a.z = vals[2]; a.w = vals[3];
  ushort4 b; b.x = vals[4]; b.y = vals[5]; b.z = vals[6]; b.w = vals[7];
  d4[0] = a; d4[1] = b;
}

// bias packed to interleaved col order: bpk[32w + 8g + u] = b_g[8w+u]
__global__ void __launch_bounds__(256) k_prep_b(
    const float* __restrict__ bi, const float* __restrict__ bf_,
    const float* __restrict__ bo, const float* __restrict__ bc,
    float* __restrict__ bpk) {
  int t = blockIdx.x * 256 + threadIdx.x;     // 2048
  int cl = t & 31, w = t >> 5;
  int u = cl & 7, gi = cl >> 3;
  const float* b = (gi == 0) ? bi : (gi == 1) ? bf_ : (gi == 2) ? bo : bc;
  bpk[t] = b[w * 8 + u];
}

// Persistent fused LSTM: 64 blocks x 4 waves; wave (g = wave-in-block, w = blockIdx)
// owns [32 rows, 32 preact cols] for every timestep. No __syncthreads, no
// threadfence in the loop: all cross-block data moves through IF via sc0 sc1.
__global__ void __launch_bounds__(256, 1) k_lstm(
    const u16* __restrict__ xbf, const u16* __restrict__ wfrag,
    const float* __restrict__ bpk, u16* hbuf,
    uint32_t* flags, float* __restrict__ out) {
  const int lane = threadIdx.x & 63;
  const int g    = threadIdx.x >> 6;          // group 0..3
  const int w    = blockIdx.x;                // unit-slice 0..63
  const int l15  = lane & 15;
  const int l4   = (lane >> 4) & 3;
  const int gh   = (lane >> 3) & 1;
  const int u    = lane & 7;

  // persistent B fragments: [768 K, 32 cols] = 48 x bf16x8 = 192 VGPR
  bf16x8 Bf[2][KS_TOT];
  {
    const bf16x8* wfb = reinterpret_cast<const bf16x8*>(wfrag);
#pragma unroll
    for (int nt = 0; nt < 2; ++nt)
#pragma unroll
      for (int ks = 0; ks < KS_TOT; ++ks)
        Bf[nt][ks] = wfb[((size_t)(w * 2 + nt) * KS_TOT + ks) * 64 + lane];
  }
  const float bias0 = bpk[w * 32 + l15];
  const float bias1 = bpk[w * 32 + 16 + l15];

  float Cst[2][4] = {};                       // cell state, unit u, rows (mt,j)
  uint32_t* fslot = flags + g * 64;           // 64 per-wave slots for this group
  uint32_t* myslot = fslot + w;

  for (int t = 0; t < T_STEPS; ++t) {
    f32x4 acc[2][2] = {};

    {                                         // x part first (K = 256): no H dep
      const u16* xr = xbf + ((size_t)(t * BATCH + g * MROWS + l15)) * EDIM + l4 * 8;
#pragma unroll
      for (int ks = 0; ks < 8; ++ks) {
        bf16x8 a0 = *reinterpret_cast<const bf16x8*>(xr + ks * 32);
        bf16x8 a1 = *reinterpret_cast<const bf16x8*>(xr + (size_t)16 * EDIM + ks * 32);
        acc[0][0] = __builtin_amdgcn_mfma_f32_16x16x32_bf16(a0, Bf[0][KS_H + ks], acc[0][0], 0, 0, 0);
        acc[0][1] = __builtin_amdgcn_mfma_f32_16x16x32_bf16(a0, Bf[1][KS_H + ks], acc[0][1], 0, 0, 0);
        acc[1][0] = __builtin_amdgcn_mfma_f32_16x16x32_bf16(a1, Bf[0][KS_H + ks], acc[1][0], 0, 0, 0);
        acc[1][1] = __builtin_amdgcn_mfma_f32_16x16x32_bf16(a1, Bf[1][KS_H + ks], acc[1][1], 0, 0, 0);
      }
    }

    if (t > 0) {
      // wait until every wave of this group has posted H^t
      int guard = 0;
      while (true) {
        uint32_t v = ifc_poll_u32(fslot + lane);
        if (__all(v >= (uint32_t)t)) break;
        if (++guard > (1 << 20)) break;       // anti-hang valve
      }

      // H part: load H^t (32 KB/wave) from IF, then 64 MFMA
      const u16* hb = hbuf + ((size_t)((t & 1) * NGROUPS + g)) * MROWS * HDIM;
      const u16* h0 = hb + (size_t)l15 * HDIM + l4 * 8;
      bf16x8 A0[KS_H], A1[KS_H];
#pragma unroll
      for (int ks = 0; ks < 8; ++ks) {        // first 16 loads
        A0[ks] = ifc_load_b128(h0 + ks * 32);
        A1[ks] = ifc_load_b128(h0 + (size_t)16 * HDIM + ks * 32);
      }
#pragma unroll
      for (int ks = 8; ks < 16; ++ks) {       // next 16 loads
        A0[ks] = ifc_load_b128(h0 + ks * 32);
        A1[ks] = ifc_load_b128(h0 + (size_t)16 * HDIM + ks * 32);
      }
      asm volatile("s_waitcnt vmcnt(16)" ::: "memory");   // first 16 arrived
      __builtin_amdgcn_sched_barrier(0);
#pragma unroll
      for (int ks = 0; ks < 8; ++ks) {
        acc[0][0] = __builtin_amdgcn_mfma_f32_16x16x32_bf16(A0[ks], Bf[0][ks], acc[0][0], 0, 0, 0);
        acc[0][1] = __builtin_amdgcn_mfma_f32_16x16x32_bf16(A0[ks], Bf[1][ks], acc[0][1], 0, 0, 0);
        acc[1][0] = __builtin_amdgcn_mfma_f32_16x16x32_bf16(A1[ks], Bf[0][ks], acc[1][0], 0, 0, 0);
        acc[1][1] = __builtin_amdgcn_mfma_f32_16x16x32_bf16(A1[ks], Bf[1][ks], acc[1][1], 0, 0, 0);
      }
      asm volatile("s_waitcnt vmcnt(0)" ::: "memory");    // rest arrived
      __builtin_amdgcn_sched_barrier(0);
#pragma unroll
      for (int ks = 8; ks < 16; ++ks) {
        acc[0][0] = __builtin_amdgcn_mfma_f32_16x16x32_bf16(A0[ks], Bf[0][ks], acc[0][0], 0, 0, 0);
        acc[0][1] = __builtin_amdgcn_mfma_f32_16x16x32_bf16(A0[ks], Bf[1][ks], acc[0][1], 0, 0, 0);
        acc[1][0] = __builtin_amdgcn_mfma_f32_16x16x32_bf16(A1[ks], Bf[0][ks], acc[1][0], 0, 0, 0);
        acc[1][1] = __builtin_amdgcn_mfma_f32_16x16x32_bf16(A1[ks], Bf[1][ks], acc[1][1], 0, 0, 0);
      }
    }

    // gating: lane pair (l, l^8) holds the 4 gates of unit u for each row
    u16* hn = hbuf + ((size_t)(((t + 1) & 1) * NGROUPS + g)) * MROWS * HDIM;
    float hv[2][4];
#pragma unroll
    for (int mt = 0; mt < 2; ++mt) {
#pragma unroll
      for (int j = 0; j < 4; ++j) {
        float p0 = acc[mt][0][j] + bias0;     // gate (gh)     of unit u
        float p1 = acc[mt][1][j] + bias1;     // gate (2+gh)   of unit u
        float q0 = __shfl_xor(p0, 8);
        float q1 = __shfl_xor(p1, 8);
        float pi = gh ? q0 : p0;
        float pf = gh ? p0 : q0;
        float po = gh ? q1 : p1;
        float pc = gh ? p1 : q1;
        float I = sigmoidf_fast(pi);
        float F = sigmoidf_fast(pf);
        float O = sigmoidf_fast(po);
        float Ct = tanhf_fast(pc);
        float c = F * Cst[mt][j] + I * Ct;
        Cst[mt][j] = c;
        hv[mt][j] = tanhf_fast(c) * O;
      }
    }

    // store H^{t+1} via IF (u32-packed pairs), release, post flag
#pragma unroll
    for (int mt = 0; mt < 2; ++mt) {
#pragma unroll
      for (int j = 0; j < 4; ++j) {
        float ho = __shfl_xor(hv[mt][j], 1);
        if (gh == 0 && (u & 1) == 0) {
          int row = mt * 16 + l4 * 4 + j;
          uint32_t pk = (uint32_t)f2bf(hv[mt][j]) | ((uint32_t)f2bf(ho) << 16);
          ifc_store_u32((uint32_t*)(hn + (size_t)row * HDIM + w * 8 + u), pk);
        }
      }
    }
    asm volatile("s_waitcnt vmcnt(0)" ::: "memory");      // release H stores to IF
    if (t + 1 < T_STEPS && lane == 0)
      ifc_store_u32(myslot, (uint32_t)(t + 1));

    // outputs (normal cached stores; off the critical sync path)
#pragma unroll
    for (int mt = 0; mt < 2; ++mt) {
#pragma unroll
      for (int j = 0; j < 4; ++j) {
        if (gh == 0) {
          int row = mt * 16 + l4 * 4 + j;
          int brow = g * MROWS + row;
          int hcol = w * 8 + u;
          out[((size_t)t * BATCH + brow) * HDIM + hcol] = hv[mt][j];
          if (t == T_STEPS - 1) {
            size_t base = (size_t)T_STEPS * BATCH * HDIM;
            out[base + (size_t)brow * HDIM + hcol] = hv[mt][j];               // H final
            out[base + (size_t)BATCH * HDIM + (size_t)brow * HDIM + hcol] = Cst[mt][j]; // C final
          }
        }
      }
    }
  }
}

extern "C" void kernel_launch(void* const* d_in, const int* in_sizes, int n_in,
                              void* d_out, int out_size, void* d_ws, size_t ws_size,
                              hipStream_t stream) {
  const float* inp = (const float*)d_in[0];
  const float* wxi = (const float*)d_in[1];
  const float* whi = (const float*)d_in[2];
  const float* bi  = (const float*)d_in[3];
  const float* wxf = (const float*)d_in[4];
  const float* whf = (const float*)d_in[5];
  const float* bf_ = (const float*)d_in[6];
  const float* wxo = (const float*)d_in[7];
  const float* who = (const float*)d_in[8];
  const float* bo  = (const float*)d_in[9];
  const float* wxc = (const float*)d_in[10];
  const float* whc = (const float*)d_in[11];
  const float* bc  = (const float*)d_in[12];

  char* ws = (char*)d_ws;
  uint32_t* flags = (uint32_t*)(ws + FLAGS_OFF);
  float*    bpk   = (float*)(ws + BIAS_OFF);
  u16*      hbuf  = (u16*)(ws + HBUF_OFF);
  u16*      wfrag = (u16*)(ws + WFRAG_OFF);
  u16*      xbf   = (u16*)(ws + XBF_OFF);
  float*    out   = (float*)d_out;

  hipMemsetAsync(flags, 0, (size_t)NGROUPS * 64 * sizeof(uint32_t), stream);
  k_prep_x<<<16384, 256, 0, stream>>>(inp, xbf);
  k_prep_w<<<768, 256, 0, stream>>>(whi, whf, who, whc, wxi, wxf, wxo, wxc, wfrag);
  k_prep_b<<<8, 256, 0, stream>>>(bi, bf_, bo, bc, bpk);
  k_lstm<<<64, 256, 0, stream>>>(xbf, wfrag, bpk, hbuf, flags, out);
}

// Round 3
// 3268.288 us; speedup vs baseline: 3.9422x; 1.6708x over previous
//
#include <hip/hip_runtime.h>
#include <hip/hip_bf16.h>
#include <stdint.h>

typedef unsigned short u16;
typedef short bf16x8 __attribute__((ext_vector_type(8)));
typedef float f32x4 __attribute__((ext_vector_type(4)));
typedef int   i32x4 __attribute__((ext_vector_type(4)));

#define T_STEPS 512
#define BATCH   128
#define EDIM    256
#define HDIM    512
#define NGROUPS 4
#define MROWS   32            // batch rows per group
#define KS_H    16            // K-slices of 32 covering Wh (512)
#define KS_TOT  24            // + Wx (256) -> K = 768

// ---- workspace layout (bytes) ----
#define FLAGS_OFF   0                          // 4*64*4 = 1024 -> pad to 16384
#define HBUF_OFF    16384                      // 2*4*64*512B = 262144
#define BIAS_OFF    (16384 + 262144)           // 2048*4 = 8192
#define WFRAG_OFF   (BIAS_OFF + 8192)          // 768*2048*2 = 3145728
#define XBF_OFF     (WFRAG_OFF + 3145728)      // 512*128*256*2 = 33554432

__device__ __forceinline__ u16 f2bf(float f) {
  union { float f; uint32_t u; } v; v.f = f;
  return (u16)((v.u + 0x7fffu + ((v.u >> 16) & 1u)) >> 16);   // RNE
}
__device__ __forceinline__ float sigmoidf_fast(float x) {
  return __builtin_amdgcn_rcpf(1.0f + __builtin_amdgcn_exp2f(-1.442695041f * x));
}
__device__ __forceinline__ float tanhf_fast(float x) {
  return 1.0f - 2.0f * __builtin_amdgcn_rcpf(1.0f + __builtin_amdgcn_exp2f(2.885390082f * x));
}

// inputs fp32 -> bf16, same [T*B, E] row-major layout.
__global__ void __launch_bounds__(256) k_prep_x(const float* __restrict__ in,
                                                u16* __restrict__ out) {
  int i = blockIdx.x * 256 + threadIdx.x;
  float4 v = reinterpret_cast<const float4*>(in)[i];
  ushort4 o; o.x = f2bf(v.x); o.y = f2bf(v.y); o.z = f2bf(v.z); o.w = f2bf(v.w);
  reinterpret_cast<ushort4*>(out)[i] = o;
}

// Pack [Wh;Wx] into per-wave MFMA B-fragment layout (bf16), gate-interleaved
// col(w,u,g) = 32w + 8g + u, unit = 8w + u.
__global__ void __launch_bounds__(256) k_prep_w(
    const float* __restrict__ whi, const float* __restrict__ whf,
    const float* __restrict__ who, const float* __restrict__ whc,
    const float* __restrict__ wxi, const float* __restrict__ wxf,
    const float* __restrict__ wxo, const float* __restrict__ wxc,
    u16* __restrict__ wfrag) {
  int t = blockIdx.x * 256 + threadIdx.x;
  int lane = t & 63;
  int rest = t >> 6;
  int ks = rest % 24;
  int nt = (rest / 24) & 1;
  int w  = rest / 48;
  int cl = nt * 16 + (lane & 15);
  int u  = cl & 7;
  int gi = cl >> 3;
  int col = w * 8 + u;
  const float* wh = (gi == 0) ? whi : (gi == 1) ? whf : (gi == 2) ? who : whc;
  const float* wx = (gi == 0) ? wxi : (gi == 1) ? wxf : (gi == 2) ? wxo : wxc;
  int kbase = ks * 32 + ((lane >> 4) & 3) * 8;
  u16 vals[8];
#pragma unroll
  for (int e = 0; e < 8; ++e) {
    int k = kbase + e;
    float s = (k < HDIM) ? wh[(size_t)k * HDIM + col]
                         : wx[(size_t)(k - HDIM) * HDIM + col];
    vals[e] = f2bf(s);
  }
  ushort4* d4 = reinterpret_cast<ushort4*>(wfrag + (size_t)t * 8);
  ushort4 a; a.x = vals[0]; a.y = vals[1]; a.z = vals[2]; a.w = vals[3];
  ushort4 b; b.x = vals[4]; b.y = vals[5]; b.z = vals[6]; b.w = vals[7];
  d4[0] = a; d4[1] = b;
}

__global__ void __launch_bounds__(256) k_prep_b(
    const float* __restrict__ bi, const float* __restrict__ bf_,
    const float* __restrict__ bo, const float* __restrict__ bc,
    float* __restrict__ bpk) {
  int t = blockIdx.x * 256 + threadIdx.x;
  int cl = t & 31, w = t >> 5;
  int u = cl & 7, gi = cl >> 3;
  const float* b = (gi == 0) ? bi : (gi == 1) ? bf_ : (gi == 2) ? bo : bc;
  bpk[t] = b[w * 8 + u];
}

// H-load batch: 2 k-slices (a0,a1 each) per batch, imm offsets {0,256,2048,2304}
#define H_ISSUE(b) do { const char* pb_ = p0 + (b) * 4096;                         \
  asm volatile("global_load_dwordx4 %0, %4, off sc0 sc1\n\t"                       \
               "global_load_dwordx4 %1, %4, off offset:256 sc0 sc1\n\t"            \
               "global_load_dwordx4 %2, %4, off offset:2048 sc0 sc1\n\t"           \
               "global_load_dwordx4 %3, %4, off offset:2304 sc0 sc1"               \
    : "=v"(Aq[b][0]), "=v"(Aq[b][1]), "=v"(Aq[b][2]), "=v"(Aq[b][3])               \
    : "v"(pb_)); } while (0)

#define H_WAIT(n) do {                                                             \
  asm volatile("s_waitcnt vmcnt(" #n ")" ::: "memory");                            \
  __builtin_amdgcn_sched_barrier(0); } while (0)

#define H_MFMA(b) do {                                                             \
  _Pragma("unroll")                                                                \
  for (int s_ = 0; s_ < 2; ++s_) {                                                 \
    int kk_ = (b) * 2 + s_;                                                        \
    bf16x8 a0_ = Aq[b][2 * s_], a1_ = Aq[b][2 * s_ + 1];                           \
    acc[0][0] = __builtin_amdgcn_mfma_f32_16x16x32_bf16(a0_, Bf[0][kk_], acc[0][0], 0, 0, 0); \
    acc[0][1] = __builtin_amdgcn_mfma_f32_16x16x32_bf16(a0_, Bf[1][kk_], acc[0][1], 0, 0, 0); \
    acc[1][0] = __builtin_amdgcn_mfma_f32_16x16x32_bf16(a1_, Bf[0][kk_], acc[1][0], 0, 0, 0); \
    acc[1][1] = __builtin_amdgcn_mfma_f32_16x16x32_bf16(a1_, Bf[1][kk_], acc[1][1], 0, 0, 0); \
  } } while (0)

// Persistent fused LSTM: 64 blocks x 4 waves; wave (g, w=blockIdx) owns
// [32 rows, 32 preact cols]. Cross-block H exchange via IF (sc0 sc1).
__global__ void __launch_bounds__(256, 1) k_lstm(
    const u16* __restrict__ xbf, const u16* __restrict__ wfrag,
    const float* __restrict__ bpk, u16* hbuf,
    uint32_t* flags, float* __restrict__ out) {
  const int lane = threadIdx.x & 63;
  const int g    = threadIdx.x >> 6;
  const int w    = blockIdx.x;
  const int l15  = lane & 15;
  const int l4   = lane >> 4;                 // 0..3
  const int gh   = (lane >> 3) & 1;
  const int u    = lane & 7;
  const int r    = lane & 31;                 // row for transpose/store phase

  __shared__ float xch[NGROUPS][256];         // per-wave 32x8 fp32 transpose buffer

  // persistent B fragments: [768 K, 32 cols] = 48 x bf16x8 = 192 VGPR, pinned
  bf16x8 Bf[2][KS_TOT];
  {
    const bf16x8* wfb = reinterpret_cast<const bf16x8*>(wfrag);
#pragma unroll
    for (int nt = 0; nt < 2; ++nt)
#pragma unroll
      for (int ks = 0; ks < KS_TOT; ++ks)
        Bf[nt][ks] = wfb[((size_t)(w * 2 + nt) * KS_TOT + ks) * 64 + lane];
  }
#pragma unroll
  for (int nt = 0; nt < 2; ++nt)
#pragma unroll
    for (int ks = 0; ks < KS_TOT; ++ks)
      asm volatile("" : "+v"(Bf[nt][ks]));    // anti-rematerialization pin

  const float bias0 = bpk[w * 32 + l15];
  const float bias1 = bpk[w * 32 + 16 + l15];

  float Cst[2][4] = {};
  uint32_t* fslot  = flags + g * 64;
  uint32_t* myslot = fslot + w;

  for (int t = 0; t < T_STEPS; ++t) {
    f32x4 acc[2][2] = {};

    {                                         // x part first (K=256): no H dep
      const u16* xr = xbf + ((size_t)(t * BATCH + g * MROWS + l15)) * EDIM + l4 * 8;
#pragma unroll
      for (int ks = 0; ks < 8; ++ks) {
        bf16x8 a0 = *reinterpret_cast<const bf16x8*>(xr + ks * 32);
        bf16x8 a1 = *reinterpret_cast<const bf16x8*>(xr + (size_t)16 * EDIM + ks * 32);
        acc[0][0] = __builtin_amdgcn_mfma_f32_16x16x32_bf16(a0, Bf[0][KS_H + ks], acc[0][0], 0, 0, 0);
        acc[0][1] = __builtin_amdgcn_mfma_f32_16x16x32_bf16(a0, Bf[1][KS_H + ks], acc[0][1], 0, 0, 0);
        acc[1][0] = __builtin_amdgcn_mfma_f32_16x16x32_bf16(a1, Bf[0][KS_H + ks], acc[1][0], 0, 0, 0);
        acc[1][1] = __builtin_amdgcn_mfma_f32_16x16x32_bf16(a1, Bf[1][KS_H + ks], acc[1][1], 0, 0, 0);
      }
    }

    if (t > 0) {
      // ---- wait for all 64 producer waves of this group ----
      uint32_t tv = (uint32_t)t;
      int guard = 0;
      while (true) {
        uint32_t v;
        asm volatile("global_load_dword %0, %1, off sc0 sc1\n\ts_waitcnt vmcnt(0)"
                     : "=v"(v) : "v"(fslot + lane) : "memory");
        if (__all(v >= tv)) break;
        __builtin_amdgcn_s_sleep(1);
        if (++guard > (1 << 18)) break;       // anti-hang valve
      }

      // ---- H^t loads (coalesced 1KB/instr) + MFMA, rolling 3-batch pipeline ----
      const char* hbase = (const char*)hbuf + ((size_t)((t & 1) * NGROUPS + g) * 64) * 512;
      const char* p0 = hbase + l4 * 512 + l15 * 16;
      bf16x8 Aq[8][4];
      H_ISSUE(0); H_ISSUE(1); H_ISSUE(2);
      H_WAIT(8);  H_MFMA(0); H_ISSUE(3);
      H_WAIT(8);  H_MFMA(1); H_ISSUE(4);
      H_WAIT(8);  H_MFMA(2); H_ISSUE(5);
      H_WAIT(8);  H_MFMA(3); H_ISSUE(6);
      H_WAIT(8);  H_MFMA(4); H_ISSUE(7);
      H_WAIT(8);  H_MFMA(5);
      H_WAIT(4);  H_MFMA(6);
      H_WAIT(0);  H_MFMA(7);
    }

    // ---- gating: lane pair (l, l^8) holds the 4 gates of unit u per row ----
    float hv[2][4];
#pragma unroll
    for (int mt = 0; mt < 2; ++mt) {
#pragma unroll
      for (int j = 0; j < 4; ++j) {
        float p0g = acc[mt][0][j] + bias0;
        float p1g = acc[mt][1][j] + bias1;
        float q0 = __shfl_xor(p0g, 8);
        float q1 = __shfl_xor(p1g, 8);
        float pi = gh ? q0 : p0g;
        float pf = gh ? p0g : q0;
        float po = gh ? q1 : p1g;
        float pc = gh ? p1g : q1;
        float I = sigmoidf_fast(pi);
        float F = sigmoidf_fast(pf);
        float O = sigmoidf_fast(po);
        float Ct = tanhf_fast(pc);
        float c = F * Cst[mt][j] + I * Ct;
        Cst[mt][j] = c;
        hv[mt][j] = tanhf_fast(c) * O;
      }
    }

    // ---- LDS transpose: (row scattered over lanes) -> (row contiguous per lane) ----
#pragma unroll
    for (int mt = 0; mt < 2; ++mt)
#pragma unroll
      for (int j = 0; j < 4; ++j)
        if (gh == 0) xch[g][(mt * 16 + l4 * 4 + j) * 8 + u] = hv[mt][j];
    asm volatile("s_waitcnt lgkmcnt(0)" ::: "memory");
    __builtin_amdgcn_sched_barrier(0);
    float4 rlo = *reinterpret_cast<const float4*>(&xch[g][r * 8]);
    float4 rhi = *reinterpret_cast<const float4*>(&xch[g][r * 8 + 4]);

    // ---- coalesced stores: hbuf (1 instr, IF-coherent) + out (2 instr, cached) ----
    char* hbw = (char*)hbuf + ((size_t)(((t + 1) & 1) * NGROUPS + g) * 64 + w) * 512;
    if (lane < 32) {
      uint32_t d0, d1, d2, d3;
      asm("v_cvt_pk_bf16_f32 %0, %1, %2" : "=v"(d0) : "v"(rlo.x), "v"(rlo.y));
      asm("v_cvt_pk_bf16_f32 %0, %1, %2" : "=v"(d1) : "v"(rlo.z), "v"(rlo.w));
      asm("v_cvt_pk_bf16_f32 %0, %1, %2" : "=v"(d2) : "v"(rhi.x), "v"(rhi.y));
      asm("v_cvt_pk_bf16_f32 %0, %1, %2" : "=v"(d3) : "v"(rhi.z), "v"(rhi.w));
      i32x4 pk; pk[0] = (int)d0; pk[1] = (int)d1; pk[2] = (int)d2; pk[3] = (int)d3;
      asm volatile("global_store_dwordx4 %0, %1, off sc0 sc1"
                   :: "v"(hbw + r * 16), "v"(pk) : "memory");
    } else {
      float* orow = out + ((size_t)t * BATCH + g * MROWS + r) * HDIM + w * 8;
      *reinterpret_cast<float4*>(orow)     = rlo;
      *reinterpret_cast<float4*>(orow + 4) = rhi;
      if (t == T_STEPS - 1) {
        float* frow = out + (size_t)T_STEPS * BATCH * HDIM
                          + ((size_t)g * MROWS + r) * HDIM + w * 8;
        *reinterpret_cast<float4*>(frow)     = rlo;
        *reinterpret_cast<float4*>(frow + 4) = rhi;
      }
    }

    asm volatile("s_waitcnt vmcnt(0)" ::: "memory");      // release all stores
    if (t + 1 < T_STEPS && lane == 0) {
      int tp1 = t + 1;
      asm volatile("global_store_dword %0, %1, off sc0 sc1"
                   :: "v"(myslot), "v"(tp1) : "memory");
    }
  }

  // final C (scattered, once)
  if (gh == 0) {
    size_t cbase = (size_t)T_STEPS * BATCH * HDIM + (size_t)BATCH * HDIM;
#pragma unroll
    for (int mt = 0; mt < 2; ++mt)
#pragma unroll
      for (int j = 0; j < 4; ++j)
        out[cbase + ((size_t)g * MROWS + mt * 16 + l4 * 4 + j) * HDIM + w * 8 + u] = Cst[mt][j];
  }
}

extern "C" void kernel_launch(void* const* d_in, const int* in_sizes, int n_in,
                              void* d_out, int out_size, void* d_ws, size_t ws_size,
                              hipStream_t stream) {
  const float* inp = (const float*)d_in[0];
  const float* wxi = (const float*)d_in[1];
  const float* whi = (const float*)d_in[2];
  const float* bi  = (const float*)d_in[3];
  const float* wxf = (const float*)d_in[4];
  const float* whf = (const float*)d_in[5];
  const float* bf_ = (const float*)d_in[6];
  const float* wxo = (const float*)d_in[7];
  const float* who = (const float*)d_in[8];
  const float* bo  = (const float*)d_in[9];
  const float* wxc = (const float*)d_in[10];
  const float* whc = (const float*)d_in[11];
  const float* bc  = (const float*)d_in[12];

  char* ws = (char*)d_ws;
  uint32_t* flags = (uint32_t*)(ws + FLAGS_OFF);
  float*    bpk   = (float*)(ws + BIAS_OFF);
  u16*      hbuf  = (u16*)(ws + HBUF_OFF);
  u16*      wfrag = (u16*)(ws + WFRAG_OFF);
  u16*      xbf   = (u16*)(ws + XBF_OFF);
  float*    out   = (float*)d_out;

  hipMemsetAsync(flags, 0, (size_t)NGROUPS * 64 * sizeof(uint32_t), stream);
  k_prep_x<<<16384, 256, 0, stream>>>(inp, xbf);
  k_prep_w<<<768, 256, 0, stream>>>(whi, whf, who, whc, wxi, wxf, wxo, wxc, wfrag);
  k_prep_b<<<8, 256, 0, stream>>>(bi, bf_, bo, bc, bpk);
  k_lstm<<<64, 256, 0, stream>>>(xbf, wfrag, bpk, hbuf, flags, out);
}